// Round 19
// baseline (498.859 us; speedup 1.0000x reference)
//
#include <hip/hip_runtime.h>

#define NG 64
#define RES 64
#define RES3 (RES*RES*RES)
#define NODES 128
#define NBINS 262144            // 64^3 spatial bins (~4 pts/bin)
#define FBLOCK 512
#define LDS_PITCH 132

#define PDIM 67
#define PZSTR 4489              // 67*67
#define PGSTR 300763            // 67^3 cells per grid
#define PFOLD 4557              // PZSTR + PDIM + 1 (pad offset fold)

typedef short    short8 __attribute__((ext_vector_type(8)));
typedef float    f32x16 __attribute__((ext_vector_type(16)));
typedef float    f32x4  __attribute__((ext_vector_type(4)));
typedef unsigned uint4v __attribute__((ext_vector_type(4)));

__device__ __forceinline__ float lrelu(float v) { return fmaxf(v, 0.2f * v); }

__device__ __forceinline__ unsigned cvtpk(float lo, float hi) {
    unsigned r;
    asm("v_cvt_pk_bf16_f32 %0, %1, %2" : "=v"(r) : "v"(lo), "v"(hi));
    return r;
}
__device__ __forceinline__ float lo16f(unsigned u) { return __uint_as_float(u << 16); }
__device__ __forceinline__ float hi16f(unsigned u) { return __uint_as_float(u & 0xffff0000u); }

// permlane32_swap: new_x[32:63] = old_y[0:31]; new_y[0:31] = old_x[32:63]
__device__ __forceinline__ void swap32(unsigned &x, unsigned &y) {
    auto rr = __builtin_amdgcn_permlane32_swap(x, y, false, false);
    x = rr[0]; y = rr[1];
}

__device__ __forceinline__ int bin_of(float x, float y, float z) {
    int bx = min(max((int)((x + 1.0f) * 32.0f), 0), 63);
    int by = min(max((int)((y + 1.0f) * 32.0f), 0), 63);
    int bz = min(max((int)((z + 1.0f) * 32.0f), 0), 63);
    return (bz << 12) | (by << 6) | bx;   // bx fastest: matches grid x-innermost
}

__device__ __forceinline__ int xcd_swz(int bid, int nblocks) {
    const int q = nblocks >> 3, r = nblocks & 7;
    const int xcd = bid & 7, idx = bid >> 3;
    return (xcd < r ? xcd * (q + 1) : r * (q + 1) + (xcd - r) * q) + idx;
}

// ---------------------------------------------------------------- sort
__global__ void hist_k(const float* __restrict__ xs, unsigned* __restrict__ cnt, int npts) {
    int n = blockIdx.x * blockDim.x + threadIdx.x;
    if (n >= npts) return;
    atomicAdd(&cnt[bin_of(xs[n*3], xs[n*3+1], xs[n*3+2])], 1u);
}

// stage 1: per-block exclusive scan of 1024 bins; block totals to bsum
__global__ void scan1_k(const unsigned* __restrict__ cnt, unsigned* __restrict__ offs,
                        unsigned* __restrict__ bsum) {
    __shared__ unsigned wsum[4];
    const int t = threadIdx.x, lane = t & 63, wid = t >> 6;
    const int base = blockIdx.x * 1024 + t * 4;
    const uint4v v = *(const uint4v*)(cnt + base);
    const unsigned run = v.x + v.y + v.z + v.w;
    unsigned inc = run;
    #pragma unroll
    for (int d = 1; d < 64; d <<= 1) {
        const unsigned u = __shfl_up(inc, d);
        if (lane >= d) inc += u;
    }
    if (lane == 63) wsum[wid] = inc;
    __syncthreads();
    unsigned wbase = 0;
    #pragma unroll
    for (int i = 0; i < 4; ++i) wbase += (i < wid) ? wsum[i] : 0u;
    const unsigned pre = wbase + inc - run;
    uint4v o;
    o.x = pre; o.y = o.x + v.x; o.z = o.y + v.y; o.w = o.z + v.z;
    *(uint4v*)(offs + base) = o;
    if (t == 255) bsum[blockIdx.x] = wbase + inc;
}

// stage 2: exclusive scan of 256 block totals
__global__ void scan2_k(const unsigned* __restrict__ bsum, unsigned* __restrict__ bbase) {
    __shared__ unsigned wsum[4];
    const int t = threadIdx.x, lane = t & 63, wid = t >> 6;
    const unsigned v = bsum[t];
    unsigned inc = v;
    #pragma unroll
    for (int d = 1; d < 64; d <<= 1) {
        const unsigned u = __shfl_up(inc, d);
        if (lane >= d) inc += u;
    }
    if (lane == 63) wsum[wid] = inc;
    __syncthreads();
    unsigned wbase = 0;
    #pragma unroll
    for (int i = 0; i < 4; ++i) wbase += (i < wid) ? wsum[i] : 0u;
    bbase[t] = wbase + inc - v;
}

// stage 3: add block bases
__global__ void scan3_k(unsigned* __restrict__ offs, const unsigned* __restrict__ bbase) {
    const unsigned add = bbase[blockIdx.x];
    uint4v* o4 = (uint4v*)(offs) + blockIdx.x * 256 + threadIdx.x;
    uint4v v = *o4;
    v.x += add; v.y += add; v.z += add; v.w += add;
    *o4 = v;
}

__global__ void scatter_k(const float* __restrict__ xs, unsigned* __restrict__ offs,
                          float4* __restrict__ sp, int npts) {
    int n = blockIdx.x * blockDim.x + threadIdx.x;
    if (n >= npts) return;
    float x = xs[n*3], y = xs[n*3+1], z = xs[n*3+2];
    unsigned p = atomicAdd(&offs[bin_of(x, y, z)], 1u);
    sp[p] = make_float4(x, y, z, __int_as_float(n));
}

// ---------------------------------------------------------------- padded grid repack (wave-per-row)
__global__ __launch_bounds__(256, 8)
void repack_pad_k(const float* __restrict__ g, float2* __restrict__ wg) {
    const int gz = blockIdx.x;              // NG*PDIM blocks
    const int gi = gz / PDIM;
    const int zp = gz - gi * PDIM;
    const float* base = g + ((size_t)gi << 19);
    float2* dst = wg + (size_t)gi * PGSTR + (size_t)zp * PZSTR;
    const int zr = zp - 1;
    const bool zok = (unsigned)zr < 64u;
    const int w    = threadIdx.x >> 6;
    const int lane = threadIdx.x & 63;
    for (int yp = w; yp < PDIM; yp += 4) {
        const int yr = yp - 1;
        const bool rowok = zok && (unsigned)yr < 64u;
        float2 v = make_float2(0.0f, 0.0f);
        if (rowok) {
            const int o = (zr * 64 + yr) * 64 + lane;
            v.x = base[o]; v.y = base[o + RES3];
        }
        float2* drow = dst + yp * PDIM;
        drow[1 + lane] = v;                                  // xp = 1..64
        if (lane < 3) drow[lane == 0 ? 0 : 64 + lane] = make_float2(0.0f, 0.0f); // xp 0,65,66
    }
}

// ---------------------------------------------------------------- weight/bias/coef pre-pack
__global__ void packw_k(const float* __restrict__ W0, const float* __restrict__ W1,
                        const float* __restrict__ b0, const float* __restrict__ b1,
                        const float* __restrict__ W2,
                        const float* __restrict__ scales, const float* __restrict__ trans,
                        unsigned* __restrict__ wp0, unsigned* __restrict__ wp1,
                        float* __restrict__ b0p, float* __restrict__ b1p, float* __restrict__ w2p,
                        float4* __restrict__ coefA, float4* __restrict__ coefB)
{
    const int i = blockIdx.x * 256 + threadIdx.x;
    if (i < 8192) {
        const int q = i & 3, l = (i >> 2) & 63, s = (i >> 8) & 7, jt = i >> 11;
        const int j  = jt * 32 + (l & 31);
        const int k0 = s * 16 + (l >> 5) * 8 + q * 2;
        wp0[i] = cvtpk(W0[j*128 + k0], W0[j*128 + k0 + 1]);
        wp1[i] = cvtpk(W1[j*128 + k0], W1[j*128 + k0 + 1]);
    } else if (i < 8320) {
        const int t = i - 8192;
        const int r = t & 15, h = (t >> 4) & 1, jt = t >> 5;
        const int f = 32*jt + (r & 3) + 8*(r >> 2) + 4*h;
        b0p[t] = b0[f]; b1p[t] = b1[f]; w2p[t] = W2[f];
    } else if (i < 8384) {
        const int g = i - 8320;
        constexpr float K = 31.5f / 1.48f;
        coefA[g] = make_float4(scales[g*3+0]*K, scales[g*3+1]*K, scales[g*3+2]*K, 0.0f);
        coefB[g] = make_float4(fmaf(trans[g*3+0], K, 31.5f),
                               fmaf(trans[g*3+1], K, 31.5f),
                               fmaf(trans[g*3+2], K, 31.5f), 0.0f);
    }
}

// ---------------------------------------------------------------- fused gather + MLP (weights in LDS)
// 1024 thr = 16 waves x 32 pts; lanes p/p+32 split the 64 grids of point p.
// 64 KB LDS + <=64 VGPR -> 2 blocks/CU = 32 waves/CU (full occupancy).
__global__ __launch_bounds__(1024, 2)
void fusedw_k(const float4* __restrict__ sp,
              const float2* __restrict__ gpad,
              const float4* __restrict__ coefA,
              const float4* __restrict__ coefB,
              const uint4v* __restrict__ wp0,
              const uint4v* __restrict__ wp1,
              const float*  __restrict__ b0p,
              const float*  __restrict__ b1p,
              const float*  __restrict__ w2p,
              const float*  __restrict__ b2,
              float* __restrict__ out, int npts, int nblocks)
{
    __shared__ uint4v sW0[2048];   // 32 KB
    __shared__ uint4v sW1[2048];   // 32 KB

    const int tid = threadIdx.x;
    #pragma unroll
    for (int i = 0; i < 2; ++i) {
        sW0[tid + 1024*i] = wp0[tid + 1024*i];
        sW1[tid + 1024*i] = wp1[tid + 1024*i];
    }

    const int bid = xcd_swz(blockIdx.x, nblocks);
    const int w   = tid >> 6;              // 0..15
    const int l   = tid & 63;
    const int p31 = l & 31;
    const int h   = l >> 5;
    const int h4  = h * 4;

    const int pidx = bid * 512 + w * 32 + p31;
    const float4 P = sp[min(pidx, npts - 1)];
    const float px = P.x, py = P.y, pz = P.z;

    // layer-0 accumulators, bias folded into C-init
    f32x16 acc[4];
    #pragma unroll
    for (int jt = 0; jt < 4; ++jt)
        #pragma unroll
        for (int q4 = 0; q4 < 4; ++q4) {
            const float4 bv = *reinterpret_cast<const float4*>(b0p + jt*32 + h*16 + q4*4);
            acc[jt][q4*4+0] = bv.x; acc[jt][q4*4+1] = bv.y;
            acc[jt][q4*4+2] = bv.z; acc[jt][q4*4+3] = bv.w;
        }

    const char* gb = (const char*)gpad;
    __syncthreads();   // weights staged

    #pragma unroll 1
    for (int s = 0; s < 8; ++s) {
        unsigned fr[4];
        #pragma unroll
        for (int gi = 0; gi < 4; ++gi) {
            const int g = s*8 + h4 + gi;           // this lane's grid
            const float4 cA = coefA[g];
            const float4 cB = coefB[g];
            float fx = fmaf(px, cA.x, cB.x);
            float fy = fmaf(py, cA.y, cB.y);
            float fz = fmaf(pz, cA.z, cB.z);
            fx = fminf(fmaxf(fx, -1.0f), 64.0f);
            fy = fminf(fmaxf(fy, -1.0f), 64.0f);
            fz = fminf(fmaxf(fz, -1.0f), 64.0f);
            const float fx0 = floorf(fx), fy0 = floorf(fy), fz0 = floorf(fz);
            const float wx = fx - fx0, wy = fy - fy0, wz = fz - fz0;
            const int x0 = (int)fx0, y0 = (int)fy0, z0 = (int)fz0;

            const int cell = g * PGSTR + z0 * PZSTR + y0 * PDIM + x0 + PFOLD;
            const char* p = gb + (unsigned)cell * 8u;
            const f32x4 A00 = *(const f32x4*)(p);
            const f32x4 A01 = *(const f32x4*)(p + (unsigned)(PDIM*8));
            const f32x4 A10 = *(const f32x4*)(p + (unsigned)(PZSTR*8));
            const f32x4 A11 = *(const f32x4*)(p + (unsigned)((PZSTR+PDIM)*8));

            const float wx0 = 1.0f - wx, wy0 = 1.0f - wy, wz0 = 1.0f - wz;
            const float w00 = wz0*wy0, w01 = wz0*wy, w10 = wz*wy0, w11 = wz*wy;

            const float f0 = w00*fmaf(wx, A00.z, wx0*A00.x)
                           + w01*fmaf(wx, A01.z, wx0*A01.x)
                           + w10*fmaf(wx, A10.z, wx0*A10.x)
                           + w11*fmaf(wx, A11.z, wx0*A11.x);
            const float f1 = w00*fmaf(wx, A00.w, wx0*A00.y)
                           + w01*fmaf(wx, A01.w, wx0*A01.y)
                           + w10*fmaf(wx, A10.w, wx0*A10.y)
                           + w11*fmaf(wx, A11.w, wx0*A11.y);
            fr[gi] = cvtpk(f0, f1);                // k=2g lo, k=2g+1 hi
        }
        const short8 bfr = __builtin_bit_cast(short8, (uint4v){fr[0], fr[1], fr[2], fr[3]});
        #pragma unroll
        for (int jt = 0; jt < 4; ++jt) {
            const short8 wa = __builtin_bit_cast(short8, sW0[(jt*8 + s)*64 + l]);
            acc[jt] = __builtin_amdgcn_mfma_f32_32x32x16_bf16(wa, bfr, acc[jt], 0, 0, 0);
        }
    }

    // layer 1 (W*ah + W*ar) fused with layer 2 dot; B-frags recomputed per (jt2,s)
    float psum = 0.0f;
    #pragma unroll
    for (int jt2 = 0; jt2 < 4; ++jt2) {
        f32x16 a2;
        #pragma unroll
        for (int q4 = 0; q4 < 4; ++q4) {
            const float4 bv = *reinterpret_cast<const float4*>(b1p + jt2*32 + h*16 + q4*4);
            a2[q4*4+0] = bv.x; a2[q4*4+1] = bv.y;
            a2[q4*4+2] = bv.z; a2[q4*4+3] = bv.w;
        }
        #pragma unroll
        for (int s = 0; s < 8; ++s) {
            const int jt    = s >> 1;
            const int rbase = (s & 1) * 4;
            unsigned hw[4], rw[4];
            #pragma unroll
            for (int i = 0; i < 4; ++i) {
                const int rp = rbase + i;
                float v0 = acc[jt][2*rp],  v1 = acc[jt][2*rp+1];
                v0 = fmaxf(v0, 0.2f*v0);   v1 = fmaxf(v1, 0.2f*v1);
                hw[i] = cvtpk(v0, v1);
                rw[i] = cvtpk(v0 - lo16f(hw[i]), v1 - hi16f(hw[i]));
            }
            swap32(hw[0], hw[2]); swap32(hw[1], hw[3]);
            swap32(rw[0], rw[2]); swap32(rw[1], rw[3]);

            const short8 wa = __builtin_bit_cast(short8, sW1[(jt2*8 + s)*64 + l]);
            const short8 bh = __builtin_bit_cast(short8, (uint4v){hw[0], hw[1], hw[2], hw[3]});
            const short8 br = __builtin_bit_cast(short8, (uint4v){rw[0], rw[1], rw[2], rw[3]});
            a2 = __builtin_amdgcn_mfma_f32_32x32x16_bf16(wa, bh, a2, 0, 0, 0);
            a2 = __builtin_amdgcn_mfma_f32_32x32x16_bf16(wa, br, a2, 0, 0, 0);
        }
        #pragma unroll
        for (int q4 = 0; q4 < 4; ++q4) {
            const float4 wv = *reinterpret_cast<const float4*>(w2p + jt2*32 + h*16 + q4*4);
            const float* wc = (const float*)&wv;
            #pragma unroll
            for (int c = 0; c < 4; ++c) {
                float h1 = a2[q4*4+c];
                h1 = fmaxf(h1, 0.2f*h1);
                psum = fmaf(h1, wc[c], psum);
            }
        }
    }
    const float tot = psum + __shfl_xor(psum, 32);
    if (h == 0 && pidx < npts)
        out[__float_as_int(P.w)] = tot + b2[0];
}

// ---------------------------------------------------------------- tier-3: round-1 fused fallback
__global__ __launch_bounds__(FBLOCK, 2)
void amgsrn_fused(const float* __restrict__ xs, const float* __restrict__ scales,
                  const float* __restrict__ trans, const float* __restrict__ grids,
                  const float* __restrict__ W0, const float* __restrict__ b0,
                  const float* __restrict__ W1, const float* __restrict__ b1,
                  const float* __restrict__ W2, const float* __restrict__ b2,
                  float* __restrict__ out, int npts)
{
    __shared__ float sW0T[NODES * LDS_PITCH];
    __shared__ float sW1 [NODES * LDS_PITCH];
    const int tid = threadIdx.x;
    for (int i = tid; i < NODES * NODES; i += FBLOCK) {
        const int j = i >> 7, k = i & 127;
        sW0T[k * LDS_PITCH + j] = W0[i];
        sW1 [j * LDS_PITCH + k] = W1[i];
    }
    __syncthreads();
    const int n = blockIdx.x * FBLOCK + tid;
    if (n >= npts) return;
    const float px = xs[n*3], py = xs[n*3+1], pz = xs[n*3+2];
    constexpr float INV_SCALE = 1.0f / 1.48f;
    float h[NODES];
    #pragma unroll
    for (int j = 0; j < NODES; ++j) h[j] = b0[j];
    for (int g = 0; g < NG; ++g) {
        const float cx = (px * scales[g*3+0] + trans[g*3+0]) * INV_SCALE;
        const float cy = (py * scales[g*3+1] + trans[g*3+1]) * INV_SCALE;
        const float cz = (pz * scales[g*3+2] + trans[g*3+2]) * INV_SCALE;
        const float fx = (cx + 1.0f) * 31.5f, fy = (cy + 1.0f) * 31.5f, fz = (cz + 1.0f) * 31.5f;
        const float fx0 = floorf(fx), fy0 = floorf(fy), fz0 = floorf(fz);
        const float wx = fx - fx0, wy = fy - fy0, wz = fz - fz0;
        const int x0 = (int)fx0, y0 = (int)fy0, z0 = (int)fz0;
        const int xb = min(max(x0, 0), RES - 2);
        const float wx0 = ((unsigned)x0 < (unsigned)RES) ? (1.0f - wx) : 0.0f;
        const float wx1 = ((unsigned)(x0+1) < (unsigned)RES) ? wx : 0.0f;
        const float wA = (x0 == xb ? wx0 : 0.0f) + (x0 + 1 == xb ? wx1 : 0.0f);
        const float wB = (x0 == xb + 1 ? wx0 : 0.0f) + (x0 == xb ? wx1 : 0.0f);
        const float wy0 = ((unsigned)y0 < (unsigned)RES) ? (1.0f - wy) : 0.0f;
        const float wy1 = ((unsigned)(y0+1) < (unsigned)RES) ? wy : 0.0f;
        const int yc0 = min(max(y0, 0), RES-1), yc1 = min(max(y0+1, 0), RES-1);
        const float wz0 = ((unsigned)z0 < (unsigned)RES) ? (1.0f - wz) : 0.0f;
        const float wz1 = ((unsigned)(z0+1) < (unsigned)RES) ? wz : 0.0f;
        const int zc0 = min(max(z0, 0), RES-1), zc1 = min(max(z0+1, 0), RES-1);
        const float w00 = wz0*wy0, w01 = wz0*wy1, w10 = wz1*wy0, w11 = wz1*wy1;
        const int o00 = (zc0*RES+yc0)*RES+xb, o01 = (zc0*RES+yc1)*RES+xb;
        const int o10 = (zc1*RES+yc0)*RES+xb, o11 = (zc1*RES+yc1)*RES+xb;
        const float* gp = grids + (size_t)g * (2*RES3);
        const float* gq = gp + RES3;
        float f0 = w00*fmaf(wB, gp[o00+1], wA*gp[o00]);
        f0 = fmaf(w01, fmaf(wB, gp[o01+1], wA*gp[o01]), f0);
        f0 = fmaf(w10, fmaf(wB, gp[o10+1], wA*gp[o10]), f0);
        f0 = fmaf(w11, fmaf(wB, gp[o11+1], wA*gp[o11]), f0);
        float f1 = w00*fmaf(wB, gq[o00+1], wA*gq[o00]);
        f1 = fmaf(w01, fmaf(wB, gq[o01+1], wA*gq[o01]), f1);
        f1 = fmaf(w10, fmaf(wB, gq[o10+1], wA*gq[o10]), f1);
        f1 = fmaf(w11, fmaf(wB, gq[o11+1], wA*gq[o11]), f1);
        const float4* rowA = reinterpret_cast<const float4*>(&sW0T[(2*g) * LDS_PITCH]);
        const float4* rowB = reinterpret_cast<const float4*>(&sW0T[(2*g+1) * LDS_PITCH]);
        #pragma unroll
        for (int q = 0; q < NODES/4; ++q) {
            const float4 wa = rowA[q], wb = rowB[q];
            h[4*q+0] = fmaf(f1, wb.x, fmaf(f0, wa.x, h[4*q+0]));
            h[4*q+1] = fmaf(f1, wb.y, fmaf(f0, wa.y, h[4*q+1]));
            h[4*q+2] = fmaf(f1, wb.z, fmaf(f0, wa.z, h[4*q+2]));
            h[4*q+3] = fmaf(f1, wb.w, fmaf(f0, wa.w, h[4*q+3]));
        }
    }
    #pragma unroll
    for (int j = 0; j < NODES; ++j) h[j] = lrelu(h[j]);
    float oacc = b2[0];
    for (int j = 0; j < NODES; ++j) {
        const float4* row = reinterpret_cast<const float4*>(&sW1[j * LDS_PITCH]);
        float a0 = b1[j], a1 = 0.0f, a2 = 0.0f, a3 = 0.0f;
        #pragma unroll
        for (int q = 0; q < NODES/4; ++q) {
            const float4 wv = row[q];
            a0 = fmaf(h[4*q+0], wv.x, a0);
            a1 = fmaf(h[4*q+1], wv.y, a1);
            a2 = fmaf(h[4*q+2], wv.z, a2);
            a3 = fmaf(h[4*q+3], wv.w, a3);
        }
        const float sv = lrelu((a0 + a1) + (a2 + a3));
        oacc = fmaf(sv, W2[j], oacc);
    }
    out[n] = oacc;
}

// ---------------------------------------------------------------- launcher
extern "C" void kernel_launch(void* const* d_in, const int* in_sizes, int n_in,
                              void* d_out, int out_size, void* d_ws, size_t ws_size,
                              hipStream_t stream) {
    const float* xs     = (const float*)d_in[0];
    const float* scales = (const float*)d_in[1];
    const float* trans  = (const float*)d_in[2];
    const float* grids  = (const float*)d_in[3];
    const float* W0     = (const float*)d_in[4];
    const float* b0     = (const float*)d_in[5];
    const float* W1     = (const float*)d_in[6];
    const float* b1     = (const float*)d_in[7];
    const float* W2     = (const float*)d_in[8];
    const float* b2     = (const float*)d_in[9];
    float* out = (float*)d_out;

    const int npts = in_sizes[0] / 3;
    const int npad = (npts + 511) & ~511;
    const int nb   = (npts + 255) / 256;

    auto al = [](size_t v) { return (v + 255) & ~(size_t)255; };
    size_t off = 0;
    const size_t spOff    = off; off += al((size_t)npad * 16);
    const size_t cntOff   = off; off += al((size_t)NBINS * 4);
    const size_t offsOff  = off; off += al((size_t)NBINS * 4);
    const size_t bsumOff  = off; off += al(256 * 4);
    const size_t bbaseOff = off; off += al(256 * 4);
    const size_t wp0Off   = off; off += al((size_t)8192 * 4);
    const size_t wp1Off   = off; off += al((size_t)8192 * 4);
    const size_t b0pOff   = off; off += al(128 * 4);
    const size_t b1pOff   = off; off += al(128 * 4);
    const size_t w2pOff   = off; off += al(128 * 4);
    const size_t cAOff    = off; off += al(64 * 16);
    const size_t cBOff    = off; off += al(64 * 16);
    const size_t gpadOff  = off; off += al((size_t)NG * PGSTR * 8);
    const size_t needFused = off;

    if (ws_size < needFused) {
        const int fb = (npts + FBLOCK - 1) / FBLOCK;
        amgsrn_fused<<<fb, FBLOCK, 0, stream>>>(xs, scales, trans, grids,
                                                W0, b0, W1, b1, W2, b2, out, npts);
        return;
    }

    char* ws = (char*)d_ws;
    float4*   sp    = (float4*)(ws + spOff);
    unsigned* cnt   = (unsigned*)(ws + cntOff);
    unsigned* offs  = (unsigned*)(ws + offsOff);
    unsigned* bsum  = (unsigned*)(ws + bsumOff);
    unsigned* bbase = (unsigned*)(ws + bbaseOff);
    unsigned* wp0   = (unsigned*)(ws + wp0Off);
    unsigned* wp1   = (unsigned*)(ws + wp1Off);
    float*    b0p   = (float*)(ws + b0pOff);
    float*    b1p   = (float*)(ws + b1pOff);
    float*    w2p   = (float*)(ws + w2pOff);
    float4*   coefA = (float4*)(ws + cAOff);
    float4*   coefB = (float4*)(ws + cBOff);
    float2*   gpad  = (float2*)(ws + gpadOff);

    hipMemsetAsync(cnt, 0, (size_t)NBINS * 4, stream);
    packw_k<<<33, 256, 0, stream>>>(W0, W1, b0, b1, W2, scales, trans,
                                    wp0, wp1, b0p, b1p, w2p, coefA, coefB);
    repack_pad_k<<<NG * PDIM, 256, 0, stream>>>(grids, gpad);
    hist_k<<<nb, 256, 0, stream>>>(xs, cnt, npts);
    scan1_k<<<256, 256, 0, stream>>>(cnt, offs, bsum);
    scan2_k<<<1, 256, 0, stream>>>(bsum, bbase);
    scan3_k<<<256, 256, 0, stream>>>(offs, bbase);
    scatter_k<<<nb, 256, 0, stream>>>(xs, offs, sp, npts);

    const int fblocks = npad / 512;
    fusedw_k<<<fblocks, 1024, 0, stream>>>(sp, gpad, coefA, coefB,
                                           (const uint4v*)wp0, (const uint4v*)wp1,
                                           b0p, b1p, w2p, b2, out, npts, fblocks);
}

// Round 21
// 495.031 us; speedup vs baseline: 1.0077x; 1.0077x over previous
//
#include <hip/hip_runtime.h>

#define NG 64
#define RES 64
#define RES3 (RES*RES*RES)
#define NODES 128
#define NBINS 262144            // 64^3 spatial bins (~4 pts/bin)
#define FBLOCK 512
#define LDS_PITCH 132

#define PDIM 67
#define PZSTR 4489              // 67*67
#define PGSTR 300763            // 67^3 cells per grid
#define PFOLD 4557              // PZSTR + PDIM + 1 (pad offset fold)

typedef short    short8 __attribute__((ext_vector_type(8)));
typedef float    f32x16 __attribute__((ext_vector_type(16)));
typedef float    f32x4  __attribute__((ext_vector_type(4)));
typedef unsigned uint4v __attribute__((ext_vector_type(4)));

__device__ __forceinline__ float lrelu(float v) { return fmaxf(v, 0.2f * v); }

__device__ __forceinline__ unsigned cvtpk(float lo, float hi) {
    unsigned r;
    asm("v_cvt_pk_bf16_f32 %0, %1, %2" : "=v"(r) : "v"(lo), "v"(hi));
    return r;
}
__device__ __forceinline__ float lo16f(unsigned u) { return __uint_as_float(u << 16); }
__device__ __forceinline__ float hi16f(unsigned u) { return __uint_as_float(u & 0xffff0000u); }

// permlane32_swap: new_x[32:63] = old_y[0:31]; new_y[0:31] = old_x[32:63]
__device__ __forceinline__ void swap32(unsigned &x, unsigned &y) {
    auto rr = __builtin_amdgcn_permlane32_swap(x, y, false, false);
    x = rr[0]; y = rr[1];
}

__device__ __forceinline__ int bin_of(float x, float y, float z) {
    int bx = min(max((int)((x + 1.0f) * 32.0f), 0), 63);
    int by = min(max((int)((y + 1.0f) * 32.0f), 0), 63);
    int bz = min(max((int)((z + 1.0f) * 32.0f), 0), 63);
    return (bz << 12) | (by << 6) | bx;   // bx fastest: matches grid x-innermost
}

__device__ __forceinline__ int xcd_swz(int bid, int nblocks) {
    const int q = nblocks >> 3, r = nblocks & 7;
    const int xcd = bid & 7, idx = bid >> 3;
    return (xcd < r ? xcd * (q + 1) : r * (q + 1) + (xcd - r) * q) + idx;
}

// ---------------------------------------------------------------- sort
__global__ void hist_k(const float* __restrict__ xs, unsigned* __restrict__ cnt, int npts) {
    int n = blockIdx.x * blockDim.x + threadIdx.x;
    if (n >= npts) return;
    atomicAdd(&cnt[bin_of(xs[n*3], xs[n*3+1], xs[n*3+2])], 1u);
}

// stage 1: per-block exclusive scan of 1024 bins; block totals to bsum
__global__ void scan1_k(const unsigned* __restrict__ cnt, unsigned* __restrict__ offs,
                        unsigned* __restrict__ bsum) {
    __shared__ unsigned wsum[4];
    const int t = threadIdx.x, lane = t & 63, wid = t >> 6;
    const int base = blockIdx.x * 1024 + t * 4;
    const uint4v v = *(const uint4v*)(cnt + base);
    const unsigned run = v.x + v.y + v.z + v.w;
    unsigned inc = run;
    #pragma unroll
    for (int d = 1; d < 64; d <<= 1) {
        const unsigned u = __shfl_up(inc, d);
        if (lane >= d) inc += u;
    }
    if (lane == 63) wsum[wid] = inc;
    __syncthreads();
    unsigned wbase = 0;
    #pragma unroll
    for (int i = 0; i < 4; ++i) wbase += (i < wid) ? wsum[i] : 0u;
    const unsigned pre = wbase + inc - run;
    uint4v o;
    o.x = pre; o.y = o.x + v.x; o.z = o.y + v.y; o.w = o.z + v.z;
    *(uint4v*)(offs + base) = o;
    if (t == 255) bsum[blockIdx.x] = wbase + inc;
}

// stage 2: exclusive scan of 256 block totals
__global__ void scan2_k(const unsigned* __restrict__ bsum, unsigned* __restrict__ bbase) {
    __shared__ unsigned wsum[4];
    const int t = threadIdx.x, lane = t & 63, wid = t >> 6;
    const unsigned v = bsum[t];
    unsigned inc = v;
    #pragma unroll
    for (int d = 1; d < 64; d <<= 1) {
        const unsigned u = __shfl_up(inc, d);
        if (lane >= d) inc += u;
    }
    if (lane == 63) wsum[wid] = inc;
    __syncthreads();
    unsigned wbase = 0;
    #pragma unroll
    for (int i = 0; i < 4; ++i) wbase += (i < wid) ? wsum[i] : 0u;
    bbase[t] = wbase + inc - v;
}

// stage 3: add block bases
__global__ void scan3_k(unsigned* __restrict__ offs, const unsigned* __restrict__ bbase) {
    const unsigned add = bbase[blockIdx.x];
    uint4v* o4 = (uint4v*)(offs) + blockIdx.x * 256 + threadIdx.x;
    uint4v v = *o4;
    v.x += add; v.y += add; v.z += add; v.w += add;
    *o4 = v;
}

__global__ void scatter_k(const float* __restrict__ xs, unsigned* __restrict__ offs,
                          float4* __restrict__ sp, int npts) {
    int n = blockIdx.x * blockDim.x + threadIdx.x;
    if (n >= npts) return;
    float x = xs[n*3], y = xs[n*3+1], z = xs[n*3+2];
    unsigned p = atomicAdd(&offs[bin_of(x, y, z)], 1u);
    sp[p] = make_float4(x, y, z, __int_as_float(n));
}

// ---------------------------------------------------------------- padded grid repack (wave-per-row)
__global__ __launch_bounds__(256, 8)
void repack_pad_k(const float* __restrict__ g, float2* __restrict__ wg) {
    const int gz = blockIdx.x;              // NG*PDIM blocks
    const int gi = gz / PDIM;
    const int zp = gz - gi * PDIM;
    const float* base = g + ((size_t)gi << 19);
    float2* dst = wg + (size_t)gi * PGSTR + (size_t)zp * PZSTR;
    const int zr = zp - 1;
    const bool zok = (unsigned)zr < 64u;
    const int w    = threadIdx.x >> 6;
    const int lane = threadIdx.x & 63;
    for (int yp = w; yp < PDIM; yp += 4) {
        const int yr = yp - 1;
        const bool rowok = zok && (unsigned)yr < 64u;
        float2 v = make_float2(0.0f, 0.0f);
        if (rowok) {
            const int o = (zr * 64 + yr) * 64 + lane;
            v.x = base[o]; v.y = base[o + RES3];
        }
        float2* drow = dst + yp * PDIM;
        drow[1 + lane] = v;                                  // xp = 1..64
        if (lane < 3) drow[lane == 0 ? 0 : 64 + lane] = make_float2(0.0f, 0.0f); // xp 0,65,66
    }
}

// ---------------------------------------------------------------- weight/bias/coef pre-pack
__global__ void packw_k(const float* __restrict__ W0, const float* __restrict__ W1,
                        const float* __restrict__ b0, const float* __restrict__ b1,
                        const float* __restrict__ W2,
                        const float* __restrict__ scales, const float* __restrict__ trans,
                        unsigned* __restrict__ wp0, unsigned* __restrict__ wp1,
                        float* __restrict__ b0p, float* __restrict__ b1p, float* __restrict__ w2p,
                        float4* __restrict__ coefA, float4* __restrict__ coefB)
{
    const int i = blockIdx.x * 256 + threadIdx.x;
    if (i < 8192) {
        const int q = i & 3, l = (i >> 2) & 63, s = (i >> 8) & 7, jt = i >> 11;
        const int j  = jt * 32 + (l & 31);
        const int k0 = s * 16 + (l >> 5) * 8 + q * 2;
        wp0[i] = cvtpk(W0[j*128 + k0], W0[j*128 + k0 + 1]);
        wp1[i] = cvtpk(W1[j*128 + k0], W1[j*128 + k0 + 1]);
    } else if (i < 8320) {
        const int t = i - 8192;
        const int r = t & 15, h = (t >> 4) & 1, jt = t >> 5;
        const int f = 32*jt + (r & 3) + 8*(r >> 2) + 4*h;
        b0p[t] = b0[f]; b1p[t] = b1[f]; w2p[t] = W2[f];
    } else if (i < 8384) {
        const int g = i - 8320;
        constexpr float K = 31.5f / 1.48f;
        coefA[g] = make_float4(scales[g*3+0]*K, scales[g*3+1]*K, scales[g*3+2]*K, 0.0f);
        coefB[g] = make_float4(fmaf(trans[g*3+0], K, 31.5f),
                               fmaf(trans[g*3+1], K, 31.5f),
                               fmaf(trans[g*3+2], K, 31.5f), 0.0f);
    }
}

// ---------------------------------------------------------------- fused gather + MLP (weights in LDS)
// 512 thr = 8 waves x 32 pts; lanes p/p+32 split the 64 grids of point p.
// Dual 32 KB LDS weight buffers (no multiplexing — validated r18 build).
__global__ __launch_bounds__(512, 4)
void fusedw_k(const float4* __restrict__ sp,
              const float2* __restrict__ gpad,
              const float4* __restrict__ coefA,
              const float4* __restrict__ coefB,
              const uint4v* __restrict__ wp0,
              const uint4v* __restrict__ wp1,
              const float*  __restrict__ b0p,
              const float*  __restrict__ b1p,
              const float*  __restrict__ w2p,
              const float*  __restrict__ b2,
              float* __restrict__ out, int npts, int nblocks)
{
    __shared__ uint4v sW0[2048];   // 32 KB
    __shared__ uint4v sW1[2048];   // 32 KB

    const int tid = threadIdx.x;
    #pragma unroll
    for (int i = 0; i < 4; ++i) {
        sW0[tid + 512*i] = wp0[tid + 512*i];
        sW1[tid + 512*i] = wp1[tid + 512*i];
    }

    const int bid = xcd_swz(blockIdx.x, nblocks);
    const int w   = tid >> 6;
    const int l   = tid & 63;
    const int p31 = l & 31;
    const int h   = l >> 5;
    const int h4  = h * 4;

    const int pidx = bid * 256 + w * 32 + p31;
    const float4 P = sp[min(pidx, npts - 1)];
    const float px = P.x, py = P.y, pz = P.z;

    // layer-0 accumulators, bias folded into C-init
    f32x16 acc[4];
    #pragma unroll
    for (int jt = 0; jt < 4; ++jt)
        #pragma unroll
        for (int q4 = 0; q4 < 4; ++q4) {
            const float4 bv = *reinterpret_cast<const float4*>(b0p + jt*32 + h*16 + q4*4);
            acc[jt][q4*4+0] = bv.x; acc[jt][q4*4+1] = bv.y;
            acc[jt][q4*4+2] = bv.z; acc[jt][q4*4+3] = bv.w;
        }

    const char* gb = (const char*)gpad;
    __syncthreads();   // weights staged

    #pragma unroll 1
    for (int s = 0; s < 8; ++s) {
        unsigned fr[4];
        #pragma unroll
        for (int gi = 0; gi < 4; ++gi) {
            const int g = s*8 + h4 + gi;           // this lane's grid
            const float4 cA = coefA[g];
            const float4 cB = coefB[g];
            float fx = fmaf(px, cA.x, cB.x);
            float fy = fmaf(py, cA.y, cB.y);
            float fz = fmaf(pz, cA.z, cB.z);
            fx = fminf(fmaxf(fx, -1.0f), 64.0f);
            fy = fminf(fmaxf(fy, -1.0f), 64.0f);
            fz = fminf(fmaxf(fz, -1.0f), 64.0f);
            const float fx0 = floorf(fx), fy0 = floorf(fy), fz0 = floorf(fz);
            const float wx = fx - fx0, wy = fy - fy0, wz = fz - fz0;
            const int x0 = (int)fx0, y0 = (int)fy0, z0 = (int)fz0;

            const int cell = g * PGSTR + z0 * PZSTR + y0 * PDIM + x0 + PFOLD;
            const char* p = gb + (unsigned)cell * 8u;
            const f32x4 A00 = *(const f32x4*)(p);
            const f32x4 A01 = *(const f32x4*)(p + (unsigned)(PDIM*8));
            const f32x4 A10 = *(const f32x4*)(p + (unsigned)(PZSTR*8));
            const f32x4 A11 = *(const f32x4*)(p + (unsigned)((PZSTR+PDIM)*8));

            const float wx0 = 1.0f - wx, wy0 = 1.0f - wy, wz0 = 1.0f - wz;
            const float w00 = wz0*wy0, w01 = wz0*wy, w10 = wz*wy0, w11 = wz*wy;

            const float f0 = w00*fmaf(wx, A00.z, wx0*A00.x)
                           + w01*fmaf(wx, A01.z, wx0*A01.x)
                           + w10*fmaf(wx, A10.z, wx0*A10.x)
                           + w11*fmaf(wx, A11.z, wx0*A11.x);
            const float f1 = w00*fmaf(wx, A00.w, wx0*A00.y)
                           + w01*fmaf(wx, A01.w, wx0*A01.y)
                           + w10*fmaf(wx, A10.w, wx0*A10.y)
                           + w11*fmaf(wx, A11.w, wx0*A11.y);
            fr[gi] = cvtpk(f0, f1);                // k=2g lo, k=2g+1 hi
        }
        const short8 bfr = __builtin_bit_cast(short8, (uint4v){fr[0], fr[1], fr[2], fr[3]});
        #pragma unroll
        for (int jt = 0; jt < 4; ++jt) {
            const short8 wa = __builtin_bit_cast(short8, sW0[(jt*8 + s)*64 + l]);
            acc[jt] = __builtin_amdgcn_mfma_f32_32x32x16_bf16(wa, bfr, acc[jt], 0, 0, 0);
        }
    }

    // layer 1 (W*ah + W*ar) fused with layer 2 dot; B-frags recomputed per (jt2,s)
    float psum = 0.0f;
    #pragma unroll
    for (int jt2 = 0; jt2 < 4; ++jt2) {
        f32x16 a2;
        #pragma unroll
        for (int q4 = 0; q4 < 4; ++q4) {
            const float4 bv = *reinterpret_cast<const float4*>(b1p + jt2*32 + h*16 + q4*4);
            a2[q4*4+0] = bv.x; a2[q4*4+1] = bv.y;
            a2[q4*4+2] = bv.z; a2[q4*4+3] = bv.w;
        }
        #pragma unroll
        for (int s = 0; s < 8; ++s) {
            const int jt    = s >> 1;
            const int rbase = (s & 1) * 4;
            unsigned hw[4], rw[4];
            #pragma unroll
            for (int i = 0; i < 4; ++i) {
                const int rp = rbase + i;
                float v0 = acc[jt][2*rp],  v1 = acc[jt][2*rp+1];
                v0 = fmaxf(v0, 0.2f*v0);   v1 = fmaxf(v1, 0.2f*v1);
                hw[i] = cvtpk(v0, v1);
                rw[i] = cvtpk(v0 - lo16f(hw[i]), v1 - hi16f(hw[i]));
            }
            swap32(hw[0], hw[2]); swap32(hw[1], hw[3]);
            swap32(rw[0], rw[2]); swap32(rw[1], rw[3]);

            const short8 wa = __builtin_bit_cast(short8, sW1[(jt2*8 + s)*64 + l]);
            const short8 bh = __builtin_bit_cast(short8, (uint4v){hw[0], hw[1], hw[2], hw[3]});
            const short8 br = __builtin_bit_cast(short8, (uint4v){rw[0], rw[1], rw[2], rw[3]});
            a2 = __builtin_amdgcn_mfma_f32_32x32x16_bf16(wa, bh, a2, 0, 0, 0);
            a2 = __builtin_amdgcn_mfma_f32_32x32x16_bf16(wa, br, a2, 0, 0, 0);
        }
        #pragma unroll
        for (int q4 = 0; q4 < 4; ++q4) {
            const float4 wv = *reinterpret_cast<const float4*>(w2p + jt2*32 + h*16 + q4*4);
            const float* wc = (const float*)&wv;
            #pragma unroll
            for (int c = 0; c < 4; ++c) {
                float h1 = a2[q4*4+c];
                h1 = fmaxf(h1, 0.2f*h1);
                psum = fmaf(h1, wc[c], psum);
            }
        }
    }
    const float tot = psum + __shfl_xor(psum, 32);
    if (h == 0 && pidx < npts)
        out[__float_as_int(P.w)] = tot + b2[0];
}

// ---------------------------------------------------------------- tier-3: round-1 fused fallback
__global__ __launch_bounds__(FBLOCK, 2)
void amgsrn_fused(const float* __restrict__ xs, const float* __restrict__ scales,
                  const float* __restrict__ trans, const float* __restrict__ grids,
                  const float* __restrict__ W0, const float* __restrict__ b0,
                  const float* __restrict__ W1, const float* __restrict__ b1,
                  const float* __restrict__ W2, const float* __restrict__ b2,
                  float* __restrict__ out, int npts)
{
    __shared__ float sW0T[NODES * LDS_PITCH];
    __shared__ float sW1 [NODES * LDS_PITCH];
    const int tid = threadIdx.x;
    for (int i = tid; i < NODES * NODES; i += FBLOCK) {
        const int j = i >> 7, k = i & 127;
        sW0T[k * LDS_PITCH + j] = W0[i];
        sW1 [j * LDS_PITCH + k] = W1[i];
    }
    __syncthreads();
    const int n = blockIdx.x * FBLOCK + tid;
    if (n >= npts) return;
    const float px = xs[n*3], py = xs[n*3+1], pz = xs[n*3+2];
    constexpr float INV_SCALE = 1.0f / 1.48f;
    float h[NODES];
    #pragma unroll
    for (int j = 0; j < NODES; ++j) h[j] = b0[j];
    for (int g = 0; g < NG; ++g) {
        const float cx = (px * scales[g*3+0] + trans[g*3+0]) * INV_SCALE;
        const float cy = (py * scales[g*3+1] + trans[g*3+1]) * INV_SCALE;
        const float cz = (pz * scales[g*3+2] + trans[g*3+2]) * INV_SCALE;
        const float fx = (cx + 1.0f) * 31.5f, fy = (cy + 1.0f) * 31.5f, fz = (cz + 1.0f) * 31.5f;
        const float fx0 = floorf(fx), fy0 = floorf(fy), fz0 = floorf(fz);
        const float wx = fx - fx0, wy = fy - fy0, wz = fz - fz0;
        const int x0 = (int)fx0, y0 = (int)fy0, z0 = (int)fz0;
        const int xb = min(max(x0, 0), RES - 2);
        const float wx0 = ((unsigned)x0 < (unsigned)RES) ? (1.0f - wx) : 0.0f;
        const float wx1 = ((unsigned)(x0+1) < (unsigned)RES) ? wx : 0.0f;
        const float wA = (x0 == xb ? wx0 : 0.0f) + (x0 + 1 == xb ? wx1 : 0.0f);
        const float wB = (x0 == xb + 1 ? wx0 : 0.0f) + (x0 == xb ? wx1 : 0.0f);
        const float wy0 = ((unsigned)y0 < (unsigned)RES) ? (1.0f - wy) : 0.0f;
        const float wy1 = ((unsigned)(y0+1) < (unsigned)RES) ? wy : 0.0f;
        const int yc0 = min(max(y0, 0), RES-1), yc1 = min(max(y0+1, 0), RES-1);
        const float wz0 = ((unsigned)z0 < (unsigned)RES) ? (1.0f - wz) : 0.0f;
        const float wz1 = ((unsigned)(z0+1) < (unsigned)RES) ? wz : 0.0f;
        const int zc0 = min(max(z0, 0), RES-1), zc1 = min(max(z0+1, 0), RES-1);
        const float w00 = wz0*wy0, w01 = wz0*wy1, w10 = wz1*wy0, w11 = wz1*wy1;
        const int o00 = (zc0*RES+yc0)*RES+xb, o01 = (zc0*RES+yc1)*RES+xb;
        const int o10 = (zc1*RES+yc0)*RES+xb, o11 = (zc1*RES+yc1)*RES+xb;
        const float* gp = grids + (size_t)g * (2*RES3);
        const float* gq = gp + RES3;
        float f0 = w00*fmaf(wB, gp[o00+1], wA*gp[o00]);
        f0 = fmaf(w01, fmaf(wB, gp[o01+1], wA*gp[o01]), f0);
        f0 = fmaf(w10, fmaf(wB, gp[o10+1], wA*gp[o10]), f0);
        f0 = fmaf(w11, fmaf(wB, gp[o11+1], wA*gp[o11]), f0);
        float f1 = w00*fmaf(wB, gq[o00+1], wA*gq[o00]);
        f1 = fmaf(w01, fmaf(wB, gq[o01+1], wA*gq[o01]), f1);
        f1 = fmaf(w10, fmaf(wB, gq[o10+1], wA*gq[o10]), f1);
        f1 = fmaf(w11, fmaf(wB, gq[o11+1], wA*gq[o11]), f1);
        const float4* rowA = reinterpret_cast<const float4*>(&sW0T[(2*g) * LDS_PITCH]);
        const float4* rowB = reinterpret_cast<const float4*>(&sW0T[(2*g+1) * LDS_PITCH]);
        #pragma unroll
        for (int q = 0; q < NODES/4; ++q) {
            const float4 wa = rowA[q], wb = rowB[q];
            h[4*q+0] = fmaf(f1, wb.x, fmaf(f0, wa.x, h[4*q+0]));
            h[4*q+1] = fmaf(f1, wb.y, fmaf(f0, wa.y, h[4*q+1]));
            h[4*q+2] = fmaf(f1, wb.z, fmaf(f0, wa.z, h[4*q+2]));
            h[4*q+3] = fmaf(f1, wb.w, fmaf(f0, wa.w, h[4*q+3]));
        }
    }
    #pragma unroll
    for (int j = 0; j < NODES; ++j) h[j] = lrelu(h[j]);
    float oacc = b2[0];
    for (int j = 0; j < NODES; ++j) {
        const float4* row = reinterpret_cast<const float4*>(&sW1[j * LDS_PITCH]);
        float a0 = b1[j], a1 = 0.0f, a2 = 0.0f, a3 = 0.0f;
        #pragma unroll
        for (int q = 0; q < NODES/4; ++q) {
            const float4 wv = row[q];
            a0 = fmaf(h[4*q+0], wv.x, a0);
            a1 = fmaf(h[4*q+1], wv.y, a1);
            a2 = fmaf(h[4*q+2], wv.z, a2);
            a3 = fmaf(h[4*q+3], wv.w, a3);
        }
        const float sv = lrelu((a0 + a1) + (a2 + a3));
        oacc = fmaf(sv, W2[j], oacc);
    }
    out[n] = oacc;
}

// ---------------------------------------------------------------- launcher
extern "C" void kernel_launch(void* const* d_in, const int* in_sizes, int n_in,
                              void* d_out, int out_size, void* d_ws, size_t ws_size,
                              hipStream_t stream) {
    const float* xs     = (const float*)d_in[0];
    const float* scales = (const float*)d_in[1];
    const float* trans  = (const float*)d_in[2];
    const float* grids  = (const float*)d_in[3];
    const float* W0     = (const float*)d_in[4];
    const float* b0     = (const float*)d_in[5];
    const float* W1     = (const float*)d_in[6];
    const float* b1     = (const float*)d_in[7];
    const float* W2     = (const float*)d_in[8];
    const float* b2     = (const float*)d_in[9];
    float* out = (float*)d_out;

    const int npts = in_sizes[0] / 3;
    const int npad = (npts + 255) & ~255;
    const int nb   = (npts + 255) / 256;

    auto al = [](size_t v) { return (v + 255) & ~(size_t)255; };
    size_t off = 0;
    const size_t spOff    = off; off += al((size_t)npad * 16);
    const size_t cntOff   = off; off += al((size_t)NBINS * 4);
    const size_t offsOff  = off; off += al((size_t)NBINS * 4);
    const size_t bsumOff  = off; off += al(256 * 4);
    const size_t bbaseOff = off; off += al(256 * 4);
    const size_t wp0Off   = off; off += al((size_t)8192 * 4);
    const size_t wp1Off   = off; off += al((size_t)8192 * 4);
    const size_t b0pOff   = off; off += al(128 * 4);
    const size_t b1pOff   = off; off += al(128 * 4);
    const size_t w2pOff   = off; off += al(128 * 4);
    const size_t cAOff    = off; off += al(64 * 16);
    const size_t cBOff    = off; off += al(64 * 16);
    const size_t gpadOff  = off; off += al((size_t)NG * PGSTR * 8);
    const size_t needFused = off;

    if (ws_size < needFused) {
        const int fb = (npts + FBLOCK - 1) / FBLOCK;
        amgsrn_fused<<<fb, FBLOCK, 0, stream>>>(xs, scales, trans, grids,
                                                W0, b0, W1, b1, W2, b2, out, npts);
        return;
    }

    char* ws = (char*)d_ws;
    float4*   sp    = (float4*)(ws + spOff);
    unsigned* cnt   = (unsigned*)(ws + cntOff);
    unsigned* offs  = (unsigned*)(ws + offsOff);
    unsigned* bsum  = (unsigned*)(ws + bsumOff);
    unsigned* bbase = (unsigned*)(ws + bbaseOff);
    unsigned* wp0   = (unsigned*)(ws + wp0Off);
    unsigned* wp1   = (unsigned*)(ws + wp1Off);
    float*    b0p   = (float*)(ws + b0pOff);
    float*    b1p   = (float*)(ws + b1pOff);
    float*    w2p   = (float*)(ws + w2pOff);
    float4*   coefA = (float4*)(ws + cAOff);
    float4*   coefB = (float4*)(ws + cBOff);
    float2*   gpad  = (float2*)(ws + gpadOff);

    hipMemsetAsync(cnt, 0, (size_t)NBINS * 4, stream);
    packw_k<<<33, 256, 0, stream>>>(W0, W1, b0, b1, W2, scales, trans,
                                    wp0, wp1, b0p, b1p, w2p, coefA, coefB);
    repack_pad_k<<<NG * PDIM, 256, 0, stream>>>(grids, gpad);
    hist_k<<<nb, 256, 0, stream>>>(xs, cnt, npts);
    scan1_k<<<256, 256, 0, stream>>>(cnt, offs, bsum);
    scan2_k<<<1, 256, 0, stream>>>(bsum, bbase);
    scan3_k<<<256, 256, 0, stream>>>(offs, bbase);
    scatter_k<<<nb, 256, 0, stream>>>(xs, offs, sp, npts);

    const int fblocks = npad / 256;
    fusedw_k<<<fblocks, 512, 0, stream>>>(sp, gpad, coefA, coefB,
                                          (const uint4v*)wp0, (const uint4v*)wp1,
                                          b0p, b1p, w2p, b2, out, npts, fblocks);
}